// Round 4
// baseline (105.156 us; speedup 1.0000x reference)
//
#include <hip/hip_runtime.h>

typedef _Float16 h2 __attribute__((ext_vector_type(2)));
typedef _Float16 h8 __attribute__((ext_vector_type(8)));
typedef float f32x4 __attribute__((ext_vector_type(4)));

#define ZPTS 131072
#define GRPB 16384  // W chunk-group: 64 rows(k) x 128 cols(c) x 2B, XOR-swizzled

// mixing[k][i][j] fp32 -> W^T f16 [64 k][1024 c], pre-swizzled per 16KB group
// (byte ^= (k&7)<<4) so linear global_load_lds staging yields a swizzled LDS
// image => conflict-free ds_read_b128 of 16 rows at the same col range.
__global__ void etp_prep(const float* __restrict__ mix, _Float16* __restrict__ w) {
  int t = blockIdx.x * 256 + threadIdx.x;  // 8192 threads, 8 elems each
  int base = t * 8;                        // flat k*1024 + c
  int n = base >> 10;
  int c = base & 1023;
  const float4* src = reinterpret_cast<const float4*>(mix + base);
  float4 a = src[0], b = src[1];
  h8 v;
  v[0] = (_Float16)a.x; v[1] = (_Float16)a.y; v[2] = (_Float16)a.z; v[3] = (_Float16)a.w;
  v[4] = (_Float16)b.x; v[5] = (_Float16)b.y; v[6] = (_Float16)b.z; v[7] = (_Float16)b.w;
  int g = c >> 7;
  int off = ((n << 8) + ((c & 127) << 1)) ^ ((n & 7) << 4);  // 16B-granular swizzle
  *reinterpret_cast<h8*>(reinterpret_cast<char*>(w) + g * GRPB + off) = v;
}

// C[Z,64] = O[Z,1024] x W[1024,64]; O[z, i*32+j] = f1[z,i]*f2[z,j] built in regs.
// Block: 256 thr (4 waves), 128 z. Wave decomposition 2x2: wave (wr=wv&1,
// wc=wv>>1) owns 64 z (4 M-tiles) x 32 k (2 N-tiles) -> B-fragment LDS reads
// halved vs pure z-split (8KB/wave/group); A-build VALU x2 (still << HBM term).
// Grid 1024 -> 4 blocks/CU (16 waves/CU).
__global__ __launch_bounds__(256, 4) void etp_main(
    const float* __restrict__ f1, const float* __restrict__ f2,
    const _Float16* __restrict__ w, float* __restrict__ out) {
  __shared__ __align__(16) char lds[2 * GRPB];  // W double buffer
  const int tid = threadIdx.x;
  const int lane = tid & 63;
  const int wv = tid >> 6;
  const int l15 = lane & 15;
  const int lhi = lane >> 4;  // 0..3
  const int j0 = lhi << 3;
  const int wr = wv & 1;   // z-half of block
  const int wc = wv >> 1;  // k-half (32 cols of out)
  const int zw = blockIdx.x * 128 + wr * 64;

  // f2[z, j0..j0+7] per M-tile, packed to halves (prologue only).
  h2 f2h[4][4];
  int zr[4];
#pragma unroll
  for (int m = 0; m < 4; ++m) {
    int z = zw + m * 16 + l15;
    zr[m] = z;
    const float4* p = reinterpret_cast<const float4*>(f2 + z * 32 + j0);
    float4 a = p[0], b = p[1];
    f2h[m][0] = h2{(_Float16)a.x, (_Float16)a.y};
    f2h[m][1] = h2{(_Float16)a.z, (_Float16)a.w};
    f2h[m][2] = h2{(_Float16)b.x, (_Float16)b.y};
    f2h[m][3] = h2{(_Float16)b.z, (_Float16)b.w};
  }

  f32x4 acc[4][2];
#pragma unroll
  for (int m = 0; m < 4; ++m)
#pragma unroll
    for (int n = 0; n < 2; ++n) acc[m][n] = f32x4{0.f, 0.f, 0.f, 0.f};

  auto stageW = [&](int g, int p) {
#pragma unroll
    for (int q = 0; q < 4; ++q) {
      int idx = (wv << 2) + q;  // 0..15 chunks of 1KB (dest wave-uniform)
      const char* gp =
          reinterpret_cast<const char*>(w) + g * GRPB + idx * 1024 + lane * 16;
      __builtin_amdgcn_global_load_lds(
          (const __attribute__((address_space(1))) void*)gp,
          (__attribute__((address_space(3))) void*)(lds + p * GRPB + idx * 1024),
          16, 0, 0);
    }
  };

  stageW(0, 0);
  float4 f1cur[4];
#pragma unroll
  for (int m = 0; m < 4; ++m)
    f1cur[m] = *reinterpret_cast<const float4*>(f1 + zr[m] * 32);  // group 0

#pragma unroll 1
  for (int g = 0; g < 8; ++g) {
    __syncthreads();  // drains vmcnt -> W buf (g&1) and f1cur are ready
    float4 f1nxt[4];
    if (g < 7) {
      stageW(g + 1, (g + 1) & 1);
#pragma unroll
      for (int m = 0; m < 4; ++m)
        f1nxt[m] = *reinterpret_cast<const float4*>(f1 + zr[m] * 32 + (g + 1) * 4);
    }
    const char* B = lds + (g & 1) * GRPB;

#pragma unroll
    for (int cc = 0; cc < 4; ++cc) {
      h8 bf[2];
#pragma unroll
      for (int nt = 0; nt < 2; ++nt) {
        int rw = wc * 32 + nt * 16 + l15;
        int off = ((rw << 8) + ((cc * 32 + j0) << 1)) ^ ((rw & 7) << 4);
        bf[nt] = *reinterpret_cast<const h8*>(B + off);
      }
#pragma unroll
      for (int m = 0; m < 4; ++m) {
        float f1s = (cc == 0) ? f1cur[m].x
                  : (cc == 1) ? f1cur[m].y
                  : (cc == 2) ? f1cur[m].z : f1cur[m].w;
        _Float16 fh = (_Float16)f1s;
        h2 f1h = h2{fh, fh};
        union { h8 v; h2 h[4]; } af;
        af.h[0] = f1h * f2h[m][0];  // v_pk_mul_f16: O[z,c] = f1[z,i]*f2[z,j]
        af.h[1] = f1h * f2h[m][1];
        af.h[2] = f1h * f2h[m][2];
        af.h[3] = f1h * f2h[m][3];
#pragma unroll
        for (int nt = 0; nt < 2; ++nt)
          acc[m][nt] =
              __builtin_amdgcn_mfma_f32_16x16x32_f16(af.v, bf[nt], acc[m][nt], 0, 0, 0);
      }
    }
    if (g < 7) {
#pragma unroll
      for (int m = 0; m < 4; ++m) f1cur[m] = f1nxt[m];
    }
  }

  // Epilogue (R1-proven layout): D col = l15 (k within tile), row = lhi*4 + r (z).
#pragma unroll
  for (int m = 0; m < 4; ++m) {
    int zbase = zw + m * 16 + lhi * 4;
#pragma unroll
    for (int r = 0; r < 4; ++r) {
      float* o = out + (zbase + r) * 64 + wc * 32 + l15;
      o[0] = acc[m][0][r];
      o[16] = acc[m][1][r];
    }
  }
}

extern "C" void kernel_launch(void* const* d_in, const int* in_sizes, int n_in,
                              void* d_out, int out_size, void* d_ws, size_t ws_size,
                              hipStream_t stream) {
  const float* f1 = (const float*)d_in[0];
  const float* f2 = (const float*)d_in[1];
  const float* mix = (const float*)d_in[2];
  float* out = (float*)d_out;
  _Float16* w = (_Float16*)d_ws;  // 128 KB of workspace

  hipLaunchKernelGGL(etp_prep, dim3(32), dim3(256), 0, stream, mix, w);
  hipLaunchKernelGGL(etp_main, dim3(ZPTS / 128), dim3(256), 0, stream, f1, f2, w, out);
}

// Round 7
// 98.175 us; speedup vs baseline: 1.0711x; 1.0711x over previous
//
#include <hip/hip_runtime.h>

typedef _Float16 h2 __attribute__((ext_vector_type(2)));
typedef _Float16 h8 __attribute__((ext_vector_type(8)));
typedef float f32x4 __attribute__((ext_vector_type(4)));

#define ZPTS 131072
#define GRPB 16384  // W chunk-group: 64 rows(k) x 128 cols(c) x 2B, XOR-swizzled

// mixing[k][i][j] fp32 -> W^T f16 [64 k][1024 c], pre-swizzled per 16KB group
// (byte ^= (k&7)<<4) so linear global_load_lds staging yields a swizzled LDS
// image => conflict-free ds_read_b128 of 16 rows at the same col range.
__global__ void etp_prep(const float* __restrict__ mix, _Float16* __restrict__ w) {
  int t = blockIdx.x * 256 + threadIdx.x;  // 8192 threads, 8 elems each
  int base = t * 8;                        // flat k*1024 + c
  int n = base >> 10;
  int c = base & 1023;
  const float4* src = reinterpret_cast<const float4*>(mix + base);
  float4 a = src[0], b = src[1];
  h8 v;
  v[0] = (_Float16)a.x; v[1] = (_Float16)a.y; v[2] = (_Float16)a.z; v[3] = (_Float16)a.w;
  v[4] = (_Float16)b.x; v[5] = (_Float16)b.y; v[6] = (_Float16)b.z; v[7] = (_Float16)b.w;
  int g = c >> 7;
  int off = ((n << 8) + ((c & 127) << 1)) ^ ((n & 7) << 4);  // 16B-granular swizzle
  *reinterpret_cast<h8*>(reinterpret_cast<char*>(w) + g * GRPB + off) = v;
}

// C[Z,64] = O[Z,1024] x W[1024,64]; O[z, i*32+j] = f1[z,i]*f2[z,j] built in regs.
// Block: 256 thr (4 waves), 128 z; wave: 32 z (2 M-tiles) x 64 k (4 N-tiles).
// Grid 1024 -> 4 blocks/CU (16 waves/CU). f1 register-double-buffered across
// groups. HBM-bound per R1-R5 analysis: ~67 MB moved at ~floor; structural
// variants (occupancy x2, k-split, LDS-read halving) all null or negative.
__global__ __launch_bounds__(256, 4) void etp_main(
    const float* __restrict__ f1, const float* __restrict__ f2,
    const _Float16* __restrict__ w, float* __restrict__ out) {
  __shared__ __align__(16) char lds[2 * GRPB];  // W double buffer
  const int tid = threadIdx.x;
  const int lane = tid & 63;
  const int wv = tid >> 6;
  const int l15 = lane & 15;
  const int lhi = lane >> 4;  // 0..3
  const int j0 = lhi << 3;
  const int zw = blockIdx.x * 128 + wv * 32;

  // f2[z, j0..j0+7] per M-tile, packed to halves (prologue only).
  h2 f2h[2][4];
  int zr[2];
#pragma unroll
  for (int m = 0; m < 2; ++m) {
    int z = zw + m * 16 + l15;
    zr[m] = z;
    const float4* p = reinterpret_cast<const float4*>(f2 + z * 32 + j0);
    float4 a = p[0], b = p[1];
    f2h[m][0] = h2{(_Float16)a.x, (_Float16)a.y};
    f2h[m][1] = h2{(_Float16)a.z, (_Float16)a.w};
    f2h[m][2] = h2{(_Float16)b.x, (_Float16)b.y};
    f2h[m][3] = h2{(_Float16)b.z, (_Float16)b.w};
  }

  f32x4 acc[2][4];
#pragma unroll
  for (int m = 0; m < 2; ++m)
#pragma unroll
    for (int n = 0; n < 4; ++n) acc[m][n] = f32x4{0.f, 0.f, 0.f, 0.f};

  auto stageW = [&](int g, int p) {
#pragma unroll
    for (int q = 0; q < 4; ++q) {
      int idx = (wv << 2) + q;  // 0..15 chunks of 1KB (dest wave-uniform)
      const char* gp =
          reinterpret_cast<const char*>(w) + g * GRPB + idx * 1024 + lane * 16;
      __builtin_amdgcn_global_load_lds(
          (const __attribute__((address_space(1))) void*)gp,
          (__attribute__((address_space(3))) void*)(lds + p * GRPB + idx * 1024),
          16, 0, 0);
    }
  };

  stageW(0, 0);
  float4 f1cur[2];
#pragma unroll
  for (int m = 0; m < 2; ++m)
    f1cur[m] = *reinterpret_cast<const float4*>(f1 + zr[m] * 32);  // group 0

#pragma unroll 1
  for (int g = 0; g < 8; ++g) {
    __syncthreads();  // drains vmcnt -> W buf (g&1) and f1cur are ready
    float4 f1nxt[2];
    if (g < 7) {
      stageW(g + 1, (g + 1) & 1);
#pragma unroll
      for (int m = 0; m < 2; ++m)
        f1nxt[m] = *reinterpret_cast<const float4*>(f1 + zr[m] * 32 + (g + 1) * 4);
    }
    const char* B = lds + (g & 1) * GRPB;

#pragma unroll
    for (int cc = 0; cc < 4; ++cc) {
      h8 bf[4];
#pragma unroll
      for (int nt = 0; nt < 4; ++nt) {
        int rw = nt * 16 + l15;
        int off = ((rw << 8) + ((cc * 32 + j0) << 1)) ^ ((rw & 7) << 4);
        bf[nt] = *reinterpret_cast<const h8*>(B + off);
      }
#pragma unroll
      for (int m = 0; m < 2; ++m) {
        float f1s = (cc == 0) ? f1cur[m].x
                  : (cc == 1) ? f1cur[m].y
                  : (cc == 2) ? f1cur[m].z : f1cur[m].w;
        _Float16 fh = (_Float16)f1s;
        h2 f1h = h2{fh, fh};
        union { h8 v; h2 h[4]; } af;
        af.h[0] = f1h * f2h[m][0];  // v_pk_mul_f16: O[z,c] = f1[z,i]*f2[z,j]
        af.h[1] = f1h * f2h[m][1];
        af.h[2] = f1h * f2h[m][2];
        af.h[3] = f1h * f2h[m][3];
#pragma unroll
        for (int nt = 0; nt < 4; ++nt)
          acc[m][nt] =
              __builtin_amdgcn_mfma_f32_16x16x32_f16(af.v, bf[nt], acc[m][nt], 0, 0, 0);
      }
    }
    if (g < 7) {
#pragma unroll
      for (int m = 0; m < 2; ++m) f1cur[m] = f1nxt[m];
    }
  }

  // Epilogue (R1/R3-proven): D col = l15 (k in tile), row = lhi*4 + r (z).
#pragma unroll
  for (int m = 0; m < 2; ++m) {
    int zbase = zw + m * 16 + lhi * 4;
#pragma unroll
    for (int r = 0; r < 4; ++r) {
      float* o = out + (zbase + r) * 64 + l15;
      o[0] = acc[m][0][r];
      o[16] = acc[m][1][r];
      o[32] = acc[m][2][r];
      o[48] = acc[m][3][r];
    }
  }
}

extern "C" void kernel_launch(void* const* d_in, const int* in_sizes, int n_in,
                              void* d_out, int out_size, void* d_ws, size_t ws_size,
                              hipStream_t stream) {
  const float* f1 = (const float*)d_in[0];
  const float* f2 = (const float*)d_in[1];
  const float* mix = (const float*)d_in[2];
  float* out = (float*)d_out;
  _Float16* w = (_Float16*)d_ws;  // 128 KB of workspace

  hipLaunchKernelGGL(etp_prep, dim3(32), dim3(256), 0, stream, mix, w);
  hipLaunchKernelGGL(etp_main, dim3(ZPTS / 128), dim3(256), 0, stream, f1, f2, w, out);
}